// Round 6
// baseline (225.740 us; speedup 1.0000x reference)
//
#include <hip/hip_runtime.h>
#include <math.h>

// ---------------------------------------------------------------------------
// EncoderBlock, MI355X. B=16,C=128,L=1024,H=8,DK=16,K=7,NCONV=4.
// R5: k_attn restructured: key-tiling (4 chunks of 256, double-buffered LDS,
// T14 reg-prefetch) -> 47.6KB LDS = 3 blocks/CU; K stored as two d-planes
// (conflict-free reads); softmax via exp2 with additive mask (log2e folded
// into q at k_qkv); row-sums via MFMA-with-ones (lane-local inv, no shfl);
// P pack via v_perm. Other kernels unchanged from R4 (all-bf16-MFMA GEMMs).
// ---------------------------------------------------------------------------

#define ACT_N   2097152
#define OFF_ACT0 0
#define OFF_ACT1 (ACT_N)
#define OFF_QB   (2*ACT_N)   // u16[16384*16]
#define OFF_KB   (3*ACT_N)
#define OFF_VT   (4*ACT_N)
#define OFF_ABF  (5*ACT_N)   // u16[16384*128]
#define OFF_MF   (6*ACT_N)
#define OFF_WB   (6*ACT_N + 16384)            // u16[10*16384]
#define OFF_DW8  (6*ACT_N + 16384 + 81920)    // float[4096]

typedef __attribute__((ext_vector_type(8)))  short bf16x8;
typedef __attribute__((ext_vector_type(16))) float f32x16;
typedef __attribute__((ext_vector_type(4)))  float f32x4;

static __device__ __forceinline__ unsigned int f2bf(float f) {
    unsigned int u = __float_as_uint(f);
    return (u + 0x7fffu + ((u >> 16) & 1u)) >> 16;
}
static __device__ __forceinline__ unsigned int pk2(float a, float b) {
    return f2bf(a) | (f2bf(b) << 16);
}

// swizzled byte offset of 16B granule g in row `row` of a [*][128 bf16] tile
#define GOFF(row, g) (((row) << 8) + ((((g) ^ ((row) & 15))) << 4))

// 0.25 * log2(e) : folds the 1/sqrt(DK) scale AND the exp->exp2 conversion
#define QSCALE 0.3606737602222409f

// ---------------------------------------------------------------------------
// k_prep: 0..9 convert 10 weight mats fp32->bf16 [o][c]; 10 additive mask; 11 dw8
// ---------------------------------------------------------------------------
__global__ __launch_bounds__(256) void k_prep(
    const float* __restrict__ pw, const float* __restrict__ wq,
    const float* __restrict__ wk, const float* __restrict__ wv_,
    const float* __restrict__ wo, const float* __restrict__ w1,
    const float* __restrict__ w2, const unsigned char* __restrict__ mask,
    const float* __restrict__ dwsrc,
    unsigned short* __restrict__ wb, float* __restrict__ maskf,
    float* __restrict__ dw8)
{
    int blk = blockIdx.x, t = threadIdx.x;
    if (blk < 10) {
        const float* src;
        if (blk < 4)       src = pw + blk * 16384;
        else if (blk == 4) src = wq;
        else if (blk == 5) src = wk;
        else if (blk == 6) src = wv_;
        else if (blk == 7) src = wo;
        else if (blk == 8) src = w1;
        else               src = w2;
        unsigned short* dst = wb + blk * 16384;
        for (int i = t * 8; i < 16384; i += 2048) {
            float4 a = *(const float4*)(src + i);
            float4 c = *(const float4*)(src + i + 4);
            uint4 v;
            v.x = pk2(a.x, a.y); v.y = pk2(a.z, a.w);
            v.z = pk2(c.x, c.y); v.w = pk2(c.z, c.w);
            *(uint4*)(dst + i) = v;
        }
    } else if (blk == 10) {
        for (int i = t; i < 16384; i += 256)
            maskf[i] = mask[i] ? -3.0e38f : 0.0f;   // additive, exp2 domain
    } else {
        for (int i = t; i < 4096; i += 256) {
            int n = i >> 3, tap = i & 7;
            dw8[i] = (tap < 7) ? dwsrc[n * 7 + tap] : 0.0f;
        }
    }
}

// ---------------------------------------------------------------------------
// k_pe: float4-vectorized
// ---------------------------------------------------------------------------
__global__ __launch_bounds__(256) void k_pe(const float* __restrict__ x,
                                            float* __restrict__ out)
{
    int i4 = blockIdx.x * 256 + threadIdx.x;   // < 524288
    int base = i4 * 4;
    int l = base & 1023;
    int c = (base >> 10) & 127;
    float e = (float)(c & ~1);
    float fb = exp2f(e * (-13.287712379549449f / 128.0f));
    float freq = (c & 1) ? -fb : fb;
    float ph   = (c & 1) ? 1.5707963267948966f : 0.0f;
    float4 xv = ((const float4*)x)[i4];
    float4 o;
    o.x = xv.x + sinf((float)l * freq + ph);
    o.y = xv.y + sinf((float)(l + 1) * freq + ph);
    o.z = xv.z + sinf((float)(l + 2) * freq + ph);
    o.w = xv.w + sinf((float)(l + 3) * freq + ph);
    ((float4*)out)[i4] = o;
}

// ---------------------------------------------------------------------------
// k_conv (unchanged from R4)
// ---------------------------------------------------------------------------
__global__ __launch_bounds__(512) void k_conv(
    const float* __restrict__ in, float* __restrict__ out,
    const unsigned short* __restrict__ wb,   // bf16 [128 o][128 c]
    const float* __restrict__ dw8,           // [128][8]
    const float* __restrict__ pb,
    const float* __restrict__ g, const float* __restrict__ nbv)
{
    __shared__ unsigned short Wl[16384];
    __shared__ unsigned short Xl[8192];
    __shared__ float part[560];
    __shared__ float muL[70], rsL[70];

    const int b  = blockIdx.x >> 4;
    const int l0 = (blockIdx.x & 15) << 6;
    const int t  = threadIdx.x;
    const int lane = t & 63;
    const int w = __builtin_amdgcn_readfirstlane(t >> 6);
    const float* xb = in + b * 131072;

    {
        const uint4* src = (const uint4*)wb;
        #pragma unroll
        for (int i = 0; i < 4; ++i) {
            int gi = t + i * 512;
            uint4 v = src[gi];
            int row = gi >> 4, c16 = gi & 15;
            *(uint4*)((char*)Wl + GOFF(row, c16)) = v;
        }
    }
    if (t < 280) {
        int col = t >> 2, sl = t & 3;
        int gl = l0 - 3 + col;
        float s = 0.f, ss = 0.f;
        if ((unsigned)gl < 1024u) {
            for (int c = sl * 32; c < sl * 32 + 32; ++c) {
                float v = xb[c * 1024 + gl];
                s += v; ss = fmaf(v, v, ss);
            }
        }
        part[col * 8 + sl * 2]     = s;
        part[col * 8 + sl * 2 + 1] = ss;
    }
    __syncthreads();
    if (t < 70) {
        int gl = l0 - 3 + t;
        if ((unsigned)gl < 1024u) {
            float s  = part[t*8] + part[t*8+2] + part[t*8+4] + part[t*8+6];
            float ss = part[t*8+1] + part[t*8+3] + part[t*8+5] + part[t*8+7];
            float mu = s * 0.0078125f;
            float var = ss * 0.0078125f - mu * mu;
            muL[t] = mu; rsL[t] = rsqrtf(var + 1e-5f);
        } else { muL[t] = 0.f; rsL[t] = 0.f; }
    }
    __syncthreads();

    {
        const int l = lane;
        const int gl = l0 + l;
        float m[7], rf[7], vm[7];
        int pofs[7];
        #pragma unroll
        for (int j = 0; j < 7; ++j) {
            int p = gl - 3 + j;
            m[j]  = muL[l + j];
            rf[j] = rsL[l + j];
            vm[j] = ((unsigned)p < 1024u) ? 1.f : 0.f;
            pofs[j] = min(max(p, 0), 1023);
        }
        #pragma unroll
        for (int s = 0; s < 2; ++s) {
            int c0 = w * 16 + s * 8;
            unsigned int pk[4];
            #pragma unroll
            for (int cp = 0; cp < 4; ++cp) {
                float y2[2];
                #pragma unroll
                for (int ci = 0; ci < 2; ++ci) {
                    int c = c0 + cp * 2 + ci;
                    const float* xr = xb + c * 1024;
                    const float* dr = dw8 + c * 8;
                    float S1 = 0.f, S2 = 0.f;
                    #pragma unroll
                    for (int j = 0; j < 7; ++j) {
                        float xv = xr[pofs[j]];
                        float u = (xv - m[j]) * rf[j];
                        float dwv = dr[j];
                        S1 = fmaf(dwv, u,     S1);
                        S2 = fmaf(dwv, vm[j], S2);
                    }
                    y2[ci] = g[c] * S1 + nbv[c] * S2;
                }
                pk[cp] = pk2(y2[0], y2[1]);
            }
            *(uint4*)((char*)Xl + GOFF(l, (c0 >> 3))) = *(uint4*)pk;
        }
    }
    __syncthreads();

    const int l31 = lane & 31, hi = lane >> 5;
    const int ow = w >> 1, lh = w & 1;
    bf16x8 af[8];
    #pragma unroll
    for (int kc = 0; kc < 8; ++kc)
        af[kc] = *(const bf16x8*)((char*)Wl + GOFF(ow * 32 + l31, kc * 2 + hi));
    f32x16 acc;
    #pragma unroll
    for (int i = 0; i < 16; ++i) acc[i] = 0.f;
    #pragma unroll
    for (int kc = 0; kc < 8; ++kc) {
        bf16x8 bx = *(const bf16x8*)((char*)Xl + GOFF(lh * 32 + l31, kc * 2 + hi));
        acc = __builtin_amdgcn_mfma_f32_32x32x16_bf16(af[kc], bx, acc, 0, 0, 0);
    }
    float* ob = out + b * 131072;
    const int lg = l0 + lh * 32 + l31;
    #pragma unroll
    for (int r = 0; r < 16; ++r) {
        int o = ow * 32 + (r & 3) + 8 * (r >> 2) + 4 * hi;
        ob[o * 1024 + lg] = fmaxf(acc[r] + pb[o], 0.f) + xb[o * 1024 + lg];
    }
}

// ---------------------------------------------------------------------------
// k_qkv (R4 structure; q scale now 0.25*log2e for exp2-domain softmax)
// ---------------------------------------------------------------------------
__global__ __launch_bounds__(512) void k_qkv(
    const float* __restrict__ in, const unsigned short* __restrict__ wb,
    const float* __restrict__ bq, const float* __restrict__ bk,
    const float* __restrict__ bv,
    const float* __restrict__ g, const float* __restrict__ nbv,
    unsigned short* __restrict__ qb, unsigned short* __restrict__ kb,
    unsigned short* __restrict__ vt)
{
    __shared__ unsigned short Wl[16384];
    __shared__ unsigned short Xl[8192];
    __shared__ unsigned short vs[8][1280];
    __shared__ float part[1024];
    __shared__ float muL[64], rsL[64];

    const int b  = blockIdx.x >> 4;
    const int l0 = (blockIdx.x & 15) << 6;
    const int t  = threadIdx.x;
    const int lane = t & 63;
    const int w = __builtin_amdgcn_readfirstlane(t >> 6);
    const float* xb = in + b * 131072;

    {
        const uint4* src = (const uint4*)wb;
        #pragma unroll
        for (int i = 0; i < 4; ++i) {
            int gi = t + i * 512;
            uint4 v = src[gi];
            int row = gi >> 4, c16 = gi & 15;
            *(uint4*)((char*)Wl + GOFF(row, c16)) = v;
        }
    }
    {
        int col = t >> 3, sl = t & 7;
        float s = 0.f, ss = 0.f;
        for (int c = sl * 16; c < sl * 16 + 16; ++c) {
            float v = xb[c * 1024 + l0 + col];
            s += v; ss = fmaf(v, v, ss);
        }
        part[col * 16 + sl * 2]     = s;
        part[col * 16 + sl * 2 + 1] = ss;
    }
    __syncthreads();
    if (t < 64) {
        float s = 0.f, ss = 0.f;
        #pragma unroll
        for (int j = 0; j < 8; ++j) { s += part[t*16 + j*2]; ss += part[t*16 + j*2 + 1]; }
        float mu = s * 0.0078125f;
        float var = ss * 0.0078125f - mu * mu;
        muL[t] = mu; rsL[t] = rsqrtf(var + 1e-5f);
    }
    __syncthreads();
    {
        const int l = lane;
        float mu = muL[l], rs = rsL[l];
        #pragma unroll
        for (int s = 0; s < 2; ++s) {
            int c0 = w * 16 + s * 8;
            unsigned int pk[4];
            #pragma unroll
            for (int cp = 0; cp < 4; ++cp) {
                int c = c0 + cp * 2;
                float v0 = (xb[c * 1024 + l0 + l]       - mu) * rs * g[c]     + nbv[c];
                float v1 = (xb[(c + 1) * 1024 + l0 + l] - mu) * rs * g[c + 1] + nbv[c + 1];
                pk[cp] = pk2(v0, v1);
            }
            *(uint4*)((char*)Xl + GOFF(l, (c0 >> 3))) = *(uint4*)pk;
        }
    }
    __syncthreads();

    const int l31 = lane & 31, hi = lane >> 5;
    const int ow = w >> 1, lh = w & 1;
    const int lg = l0 + lh * 32 + l31;

    for (int p = 0; p < 3; ++p) {
        uint4 pw4[4];
        if (p < 2) {
            const uint4* src = (const uint4*)(wb + (p + 1) * 16384);
            #pragma unroll
            for (int i = 0; i < 4; ++i) pw4[i] = src[t + i * 512];
        }
        bf16x8 af[8];
        #pragma unroll
        for (int kc = 0; kc < 8; ++kc)
            af[kc] = *(const bf16x8*)((char*)Wl + GOFF(ow * 32 + l31, kc * 2 + hi));
        f32x16 acc;
        #pragma unroll
        for (int i = 0; i < 16; ++i) acc[i] = 0.f;
        #pragma unroll
        for (int kc = 0; kc < 8; ++kc) {
            bf16x8 bx = *(const bf16x8*)((char*)Xl + GOFF(lh * 32 + l31, kc * 2 + hi));
            acc = __builtin_amdgcn_mfma_f32_32x32x16_bf16(af[kc], bx, acc, 0, 0, 0);
        }

        if (p < 2) {
            const float* bias = (p == 0) ? bq : bk;
            unsigned short* dst = (p == 0) ? qb : kb;
            const float scl = (p == 0) ? QSCALE : 1.0f;
            unsigned int pk0[4], pk1[4];
            #pragma unroll
            for (int j2 = 0; j2 < 4; ++j2) {
                int r = j2 * 2;
                int o0 = ow * 32 + (r & 3) + 8 * (r >> 2) + 4 * hi;
                pk0[j2] = pk2((acc[r] + bias[o0]) * scl,
                              (acc[r + 1] + bias[o0 + 1]) * scl);
                int r8 = r + 8;
                int o1 = ow * 32 + (r8 & 3) + 8 * (r8 >> 2) + 4 * hi;
                pk1[j2] = pk2((acc[r8] + bias[o1]) * scl,
                              (acc[r8 + 1] + bias[o1 + 1]) * scl);
            }
            int bh0 = b * 8 + 2 * ow;
            *(uint4*)(dst + ((size_t)bh0 * 1024 + lg) * 16 + hi * 8) = *(uint4*)pk0;
            *(uint4*)(dst + ((size_t)(bh0 + 1) * 1024 + lg) * 16 + hi * 8) = *(uint4*)pk1;
        } else {
            unsigned short* vsw = vs[w];
            #pragma unroll
            for (int r = 0; r < 16; ++r) {
                int orow = (r & 3) + 8 * (r >> 2) + 4 * hi;
                int o = ow * 32 + orow;
                vsw[orow * 40 + l31] = (unsigned short)f2bf(acc[r] + bv[o]);
            }
            int d32 = l31;
            uint4 v0 = *(uint4*)(vsw + d32 * 40 + hi * 16);
            uint4 v1 = *(uint4*)(vsw + d32 * 40 + hi * 16 + 8);
            int head = 2 * ow + (d32 >> 4), dd = d32 & 15;
            unsigned short* vp = vt + ((size_t)(b * 8 + head) * 16 + dd) * 1024
                                    + l0 + lh * 32 + hi * 16;
            *(uint4*)vp = v0; *(uint4*)(vp + 8) = v1;
        }
        __syncthreads();
        if (p < 2) {
            #pragma unroll
            for (int i = 0; i < 4; ++i) {
                int gi = t + i * 512;
                int row = gi >> 4, c16 = gi & 15;
                *(uint4*)((char*)Wl + GOFF(row, c16)) = pw4[i];
            }
            __syncthreads();
        }
    }
}

// ---------------------------------------------------------------------------
// k_attn (R5): key-tiled (4 chunks x 256 keys), double-buffered LDS, T14.
// K as two d-planes (conflict-free), exp2+additive-mask softmax, row-sums
// via MFMA-with-ones (lane-local inv). 47.6KB LDS -> 3 blocks/CU.
// ---------------------------------------------------------------------------
__global__ __launch_bounds__(256) void k_attn(
    const unsigned short* __restrict__ qb, const unsigned short* __restrict__ kb,
    const unsigned short* __restrict__ vt, const float* __restrict__ madd,
    unsigned short* __restrict__ abf)
{
    __shared__ unsigned short Kl[2][4096];   // [buf][plane*2048 + key*8] 16KB
    __shared__ unsigned short Vl[2][4224];   // [buf][d*264 + key] 16.5KB
    __shared__ float Ml[1024];               // additive mask, 4KB
    __shared__ unsigned int Pl[4][640];      // per-wave P / O scratch 10KB

    const int bh = blockIdx.x >> 3;
    const int b  = bh >> 3;
    const int h  = bh & 7;
    const int qbase = (blockIdx.x & 7) << 7;
    const int t = threadIdx.x;
    const int lane = t & 63;
    const int w = t >> 6;
    const int l31 = lane & 31, hi = lane >> 5;
    const int l15 = lane & 15, h2 = lane >> 4;
    const int qw = qbase + w * 32;

    const uint4* ksrc = (const uint4*)(kb + (size_t)bh * 16384);
    const unsigned short* vsrc = vt + (size_t)bh * 16384;

    // V granule coords for this thread (2 granules)
    const int d0v = t >> 5,          ko0 = t & 31;
    const int d1v = (t + 256) >> 5,  ko1 = (t + 256) & 31;
    // K dst coords
    const int kp0 = t & 1,        kk0 = t >> 1;
    const int kp1 = t & 1,        kk1 = (t + 256) >> 1;   // (t+256)&1 == t&1

    ((float4*)Ml)[t] = ((const float4*)(madd + b * 1024))[t];

    bf16x8 qf;
    {
        uint4 qv = *(const uint4*)(qb + ((size_t)bh * 1024 + qw + l31) * 16 + hi * 8);
        union { uint4 u; bf16x8 v; } cvt; cvt.u = qv; qf = cvt.v;
    }
    bf16x8 ones;
    #pragma unroll
    for (int i = 0; i < 8; ++i) ones[i] = (short)0x3F80;

    // prologue: stage chunk 0 into buf 0
    {
        uint4 kr0 = ksrc[t], kr1 = ksrc[t + 256];
        uint4 vr0 = *(const uint4*)(vsrc + d0v * 1024 + ko0 * 8);
        uint4 vr1 = *(const uint4*)(vsrc + d1v * 1024 + ko1 * 8);
        *(uint4*)(&Kl[0][kp0 * 2048 + kk0 * 8]) = kr0;
        *(uint4*)(&Kl[0][kp1 * 2048 + kk1 * 8]) = kr1;
        *(uint4*)(&Vl[0][d0v * 264 + ko0 * 8]) = vr0;
        *(uint4*)(&Vl[0][d1v * 264 + ko1 * 8]) = vr1;
    }
    __syncthreads();

    f32x16 Z;
    #pragma unroll
    for (int i = 0; i < 16; ++i) Z[i] = 0.f;
    f32x4 O0, O1, Os0, Os1;
    #pragma unroll
    for (int i = 0; i < 4; ++i) { O0[i] = 0.f; O1[i] = 0.f; Os0[i] = 0.f; Os1[i] = 0.f; }

    unsigned int* myP = &Pl[w][0];
    int cur = 0;

    for (int ch = 0; ch < 4; ++ch) {
        uint4 kr0, kr1, vr0, vr1;
        if (ch < 3) {   // T14: issue next-chunk loads now, write after barrier
            int cb = (ch + 1) * 512;
            int vb = (ch + 1) * 256;
            kr0 = ksrc[cb + t];
            kr1 = ksrc[cb + t + 256];
            vr0 = *(const uint4*)(vsrc + d0v * 1024 + vb + ko0 * 8);
            vr1 = *(const uint4*)(vsrc + d1v * 1024 + vb + ko1 * 8);
        }
        const unsigned short* Kb = Kl[cur];
        const unsigned short* Vb = Vl[cur];
        const int kgbase = ch * 256;

        #pragma unroll 2
        for (int kc = 0; kc < 8; ++kc) {
            bf16x8 kf = *(const bf16x8*)(Kb + hi * 2048 + (kc * 32 + l31) * 8);
            f32x16 S = __builtin_amdgcn_mfma_f32_32x32x16_bf16(kf, qf, Z, 0, 0, 0);

            #pragma unroll
            for (int rg = 0; rg < 4; ++rg) {
                float4 mm = *(const float4*)(Ml + kgbase + kc * 32 + rg * 8 + hi * 4);
                float p0 = exp2f(S[rg * 4 + 0] + mm.x);
                float p1 = exp2f(S[rg * 4 + 1] + mm.y);
                float p2 = exp2f(S[rg * 4 + 2] + mm.z);
                float p3 = exp2f(S[rg * 4 + 3] + mm.w);
                uint2 pwd;
                pwd.x = __builtin_amdgcn_perm(__float_as_uint(p1),
                                              __float_as_uint(p0), 0x07060302u);
                pwd.y = __builtin_amdgcn_perm(__float_as_uint(p3),
                                              __float_as_uint(p2), 0x07060302u);
                *(uint2*)((char*)myP + l31 * 80 + rg * 16 + hi * 8) = pwd;
            }

            bf16x8 vf  = *(const bf16x8*)(Vb + l15 * 264 + kc * 32 + h2 * 8);
            bf16x8 pa0 = *(const bf16x8*)((const char*)myP + l15 * 80 + h2 * 16);
            bf16x8 pa1 = *(const bf16x8*)((const char*)myP + (16 + l15) * 80 + h2 * 16);
            O0  = __builtin_amdgcn_mfma_f32_16x16x32_bf16(pa0, vf,   O0,  0, 0, 0);
            O1  = __builtin_amdgcn_mfma_f32_16x16x32_bf16(pa1, vf,   O1,  0, 0, 0);
            Os0 = __builtin_amdgcn_mfma_f32_16x16x32_bf16(pa0, ones, Os0, 0, 0, 0);
            Os1 = __builtin_amdgcn_mfma_f32_16x16x32_bf16(pa1, ones, Os1, 0, 0, 0);
        }

        if (ch < 3) {
            __syncthreads();
            int nxt = cur ^ 1;
            *(uint4*)(&Kl[nxt][kp0 * 2048 + kk0 * 8]) = kr0;
            *(uint4*)(&Kl[nxt][kp1 * 2048 + kk1 * 8]) = kr1;
            *(uint4*)(&Vl[nxt][d0v * 264 + ko0 * 8]) = vr0;
            *(uint4*)(&Vl[nxt][d1v * 264 + ko1 * 8]) = vr1;
            __syncthreads();
            cur = nxt;
        }
    }

    // normalize: Osum holds per-q row-sums (replicated across cols) -> lane-local
    unsigned short* myP16 = (unsigned short*)myP;
    #pragma unroll
    for (int r = 0; r < 4; ++r) {
        float i0 = __builtin_amdgcn_rcpf(Os0[r] + 1e-37f);
        float i1 = __builtin_amdgcn_rcpf(Os1[r] + 1e-37f);
        myP16[(h2 * 4 + r) * 20 + l15]        = (unsigned short)f2bf(O0[r] * i0);
        myP16[(16 + h2 * 4 + r) * 20 + l15]   = (unsigned short)f2bf(O1[r] * i1);
    }
    uint4 ov = *(const uint4*)(myP16 + l31 * 20 + hi * 8);
    *(uint4*)(abf + ((size_t)(b * 1024 + qw + l31)) * 128 + h * 16 + hi * 8) = ov;
}

// ---------------------------------------------------------------------------
// k_oproj (unchanged from R4)
// ---------------------------------------------------------------------------
__global__ __launch_bounds__(512) void k_oproj(
    const unsigned short* __restrict__ abf, const unsigned short* __restrict__ wb,
    const float* __restrict__ bo, const float* __restrict__ res,
    float* __restrict__ out)
{
    __shared__ unsigned short Wl[16384];
    __shared__ unsigned short Xl[8192];
    const int b  = blockIdx.x >> 4;
    const int l0 = (blockIdx.x & 15) << 6;
    const int t  = threadIdx.x;
    const int lane = t & 63;
    const int w = __builtin_amdgcn_readfirstlane(t >> 6);

    {
        const uint4* src = (const uint4*)wb;
        #pragma unroll
        for (int i = 0; i < 4; ++i) {
            int gi = t + i * 512;
            uint4 v = src[gi];
            int row = gi >> 4, c16 = gi & 15;
            *(uint4*)((char*)Wl + GOFF(row, c16)) = v;
        }
        #pragma unroll
        for (int i = 0; i < 2; ++i) {
            int gi = t + i * 512;
            int row = gi >> 4, c16 = gi & 15;
            uint4 v = *(const uint4*)(abf + ((size_t)(b * 1024 + l0 + row)) * 128 + c16 * 8);
            *(uint4*)((char*)Xl + GOFF(row, c16)) = v;
        }
    }
    __syncthreads();

    const int l31 = lane & 31, hi = lane >> 5;
    const int ow = w >> 1, lh = w & 1;
    bf16x8 af[8];
    #pragma unroll
    for (int kc = 0; kc < 8; ++kc)
        af[kc] = *(const bf16x8*)((char*)Wl + GOFF(ow * 32 + l31, kc * 2 + hi));
    f32x16 acc;
    #pragma unroll
    for (int i = 0; i < 16; ++i) acc[i] = 0.f;
    #pragma unroll
    for (int kc = 0; kc < 8; ++kc) {
        bf16x8 bx = *(const bf16x8*)((char*)Xl + GOFF(lh * 32 + l31, kc * 2 + hi));
        acc = __builtin_amdgcn_mfma_f32_32x32x16_bf16(af[kc], bx, acc, 0, 0, 0);
    }
    const float* rb = res + b * 131072;
    float* ob = out + b * 131072;
    const int lg = l0 + lh * 32 + l31;
    #pragma unroll
    for (int r = 0; r < 16; ++r) {
        int o = ow * 32 + (r & 3) + 8 * (r >> 2) + 4 * hi;
        ob[o * 1024 + lg] = acc[r] + bo[o] + rb[o * 1024 + lg];
    }
}

// ---------------------------------------------------------------------------
// k_ffn (unchanged from R4)
// ---------------------------------------------------------------------------
__global__ __launch_bounds__(512) void k_ffn(
    const float* __restrict__ in,
    const unsigned short* __restrict__ w1b, const unsigned short* __restrict__ w2b,
    const float* __restrict__ b1, const float* __restrict__ b2,
    const float* __restrict__ g, const float* __restrict__ nbv,
    float* __restrict__ out)
{
    __shared__ unsigned short Wl[16384];
    __shared__ unsigned short Xl[8192];
    __shared__ unsigned short Xl2[8192];
    __shared__ float part[1024];
    __shared__ float muL[64], rsL[64];

    const int b  = blockIdx.x >> 4;
    const int l0 = (blockIdx.x & 15) << 6;
    const int t  = threadIdx.x;
    const int lane = t & 63;
    const int w = __builtin_amdgcn_readfirstlane(t >> 6);
    const float* xb = in + b * 131072;

    {
        const uint4* src = (const uint4*)w1b;
        #pragma unroll
        for (int i = 0; i < 4; ++i) {
            int gi = t + i * 512;
            uint4 v = src[gi];
            int row = gi >> 4, c16 = gi & 15;
            *(uint4*)((char*)Wl + GOFF(row, c16)) = v;
        }
    }
    {
        int col = t >> 3, sl = t & 7;
        float s = 0.f, ss = 0.f;
        for (int c = sl * 16; c < sl * 16 + 16; ++c) {
            float v = xb[c * 1024 + l0 + col];
            s += v; ss = fmaf(v, v, ss);
        }
        part[col * 16 + sl * 2]     = s;
        part[col * 16 + sl * 2 + 1] = ss;
    }
    __syncthreads();
    if (t < 64) {
        float s = 0.f, ss = 0.f;
        #pragma unroll
        for (int j = 0; j < 8; ++j) { s += part[t*16 + j*2]; ss += part[t*16 + j*2 + 1]; }
        float mu = s * 0.0078125f;
        float var = ss * 0.0078125f - mu * mu;
        muL[t] = mu; rsL[t] = rsqrtf(var + 1e-5f);
    }
    __syncthreads();
    {
        const int l = lane;
        float mu = muL[l], rs = rsL[l];
        #pragma unroll
        for (int s = 0; s < 2; ++s) {
            int c0 = w * 16 + s * 8;
            unsigned int pk[4];
            #pragma unroll
            for (int cp = 0; cp < 4; ++cp) {
                int c = c0 + cp * 2;
                float v0 = (xb[c * 1024 + l0 + l]       - mu) * rs * g[c]     + nbv[c];
                float v1 = (xb[(c + 1) * 1024 + l0 + l] - mu) * rs * g[c + 1] + nbv[c + 1];
                pk[cp] = pk2(v0, v1);
            }
            *(uint4*)((char*)Xl + GOFF(l, (c0 >> 3))) = *(uint4*)pk;
        }
    }
    __syncthreads();

    const int l31 = lane & 31, hi = lane >> 5;
    const int ow = w >> 1, lh = w & 1;
    const int lrow = lh * 32 + l31;

    uint4 pw4[4];
    {
        const uint4* src = (const uint4*)w2b;
        #pragma unroll
        for (int i = 0; i < 4; ++i) pw4[i] = src[t + i * 512];
    }
    {
        bf16x8 af[8];
        #pragma unroll
        for (int kc = 0; kc < 8; ++kc)
            af[kc] = *(const bf16x8*)((char*)Wl + GOFF(ow * 32 + l31, kc * 2 + hi));
        f32x16 acc;
        #pragma unroll
        for (int i = 0; i < 16; ++i) acc[i] = 0.f;
        #pragma unroll
        for (int kc = 0; kc < 8; ++kc) {
            bf16x8 bx = *(const bf16x8*)((char*)Xl + GOFF(lrow, kc * 2 + hi));
            acc = __builtin_amdgcn_mfma_f32_32x32x16_bf16(af[kc], bx, acc, 0, 0, 0);
        }
        #pragma unroll
        for (int r = 0; r < 16; ++r) {
            int o = ow * 32 + (r & 3) + 8 * (r >> 2) + 4 * hi;
            float hval = fmaxf(acc[r] + b1[o], 0.f);
            *(unsigned short*)((char*)Xl2 + (lrow << 8)
                + ((((o >> 3) ^ (lrow & 15))) << 4) + ((o & 7) * 2)) =
                (unsigned short)f2bf(hval);
        }
    }
    __syncthreads();
    {
        #pragma unroll
        for (int i = 0; i < 4; ++i) {
            int gi = t + i * 512;
            int row = gi >> 4, c16 = gi & 15;
            *(uint4*)((char*)Wl + GOFF(row, c16)) = pw4[i];
        }
    }
    __syncthreads();
    {
        bf16x8 af[8];
        #pragma unroll
        for (int kc = 0; kc < 8; ++kc)
            af[kc] = *(const bf16x8*)((char*)Wl + GOFF(ow * 32 + l31, kc * 2 + hi));
        f32x16 acc;
        #pragma unroll
        for (int i = 0; i < 16; ++i) acc[i] = 0.f;
        #pragma unroll
        for (int kc = 0; kc < 8; ++kc) {
            bf16x8 bx = *(const bf16x8*)((char*)Xl2 + GOFF(lrow, kc * 2 + hi));
            acc = __builtin_amdgcn_mfma_f32_32x32x16_bf16(af[kc], bx, acc, 0, 0, 0);
        }
        float* ob = out + b * 131072;
        const int lg = l0 + lrow;
        #pragma unroll
        for (int r = 0; r < 16; ++r) {
            int o = ow * 32 + (r & 3) + 8 * (r >> 2) + 4 * hi;
            ob[o * 1024 + lg] = acc[r] + b2[o] + xb[o * 1024 + lg];
        }
    }
}

// ---------------------------------------------------------------------------
extern "C" void kernel_launch(void* const* d_in, const int* in_sizes, int n_in,
                              void* d_out, int out_size, void* d_ws, size_t ws_size,
                              hipStream_t stream)
{
    const float* x    = (const float*)d_in[0];
    const unsigned char* mask = (const unsigned char*)d_in[1];
    const float* dw_w = (const float*)d_in[2];
    const float* pw_w = (const float*)d_in[3];
    const float* pw_b = (const float*)d_in[4];
    const float* ng   = (const float*)d_in[5];
    const float* nb   = (const float*)d_in[6];
    const float* wq   = (const float*)d_in[7];
    const float* bq   = (const float*)d_in[8];
    const float* wk   = (const float*)d_in[9];
    const float* bk   = (const float*)d_in[10];
    const float* wv   = (const float*)d_in[11];
    const float* bv   = (const float*)d_in[12];
    const float* wo   = (const float*)d_in[13];
    const float* bo   = (const float*)d_in[14];
    const float* w1   = (const float*)d_in[15];
    const float* b1   = (const float*)d_in[16];
    const float* w2   = (const float*)d_in[17];
    const float* b2   = (const float*)d_in[18];

    float* ws   = (float*)d_ws;
    float* act0 = ws + OFF_ACT0;
    float* act1 = ws + OFF_ACT1;
    unsigned short* qb  = (unsigned short*)(ws + OFF_QB);
    unsigned short* kbp = (unsigned short*)(ws + OFF_KB);
    unsigned short* vtp = (unsigned short*)(ws + OFF_VT);
    unsigned short* abf = (unsigned short*)(ws + OFF_ABF);
    float* mf   = ws + OFF_MF;
    unsigned short* wb = (unsigned short*)(ws + OFF_WB);
    float* dw8  = ws + OFF_DW8;

    k_prep<<<12, 256, 0, stream>>>(pw_w, wq, wk, wv, wo, w1, w2, mask, dw_w,
                                   wb, mf, dw8);
    k_pe<<<2048, 256, 0, stream>>>(x, act0);

    k_conv<<<256, 512, 0, stream>>>(act0, act1, wb + 0 * 16384, dw8 + 0,
                                    pw_b + 0,   ng + 0,   nb + 0);
    k_conv<<<256, 512, 0, stream>>>(act1, act0, wb + 1 * 16384, dw8 + 1024,
                                    pw_b + 128, ng + 128, nb + 128);
    k_conv<<<256, 512, 0, stream>>>(act0, act1, wb + 2 * 16384, dw8 + 2048,
                                    pw_b + 256, ng + 256, nb + 256);
    k_conv<<<256, 512, 0, stream>>>(act1, act0, wb + 3 * 16384, dw8 + 3072,
                                    pw_b + 384, ng + 384, nb + 384);

    k_qkv<<<256, 512, 0, stream>>>(act0, wb + 4 * 16384, bq, bk, bv,
                                   ng + 4 * 128, nb + 4 * 128, qb, kbp, vtp);
    k_attn<<<1024, 256, 0, stream>>>(qb, kbp, vtp, mf, abf);
    k_oproj<<<256, 512, 0, stream>>>(abf, wb + 7 * 16384, bo, act0, act1);
    k_ffn<<<256, 512, 0, stream>>>(act1, wb + 8 * 16384, wb + 9 * 16384,
                                   b1, b2, ng + 5 * 128, nb + 5 * 128,
                                   (float*)d_out);
}

// Round 7
// 211.483 us; speedup vs baseline: 1.0674x; 1.0674x over previous
//
#include <hip/hip_runtime.h>
#include <math.h>

// ---------------------------------------------------------------------------
// EncoderBlock, MI355X. B=16,C=128,L=1024,H=8,DK=16,K=7,NCONV=4.
// R6: k_attn only: single-buffer LDS (30.25KB -> 5 blocks/CU; VGPR caps occ
// at 16 waves/CU) with T14 reg-prefetch kept; exp via __builtin_amdgcn_exp2f
// (R5's exp2f may have been a slow libm path); s_setprio around PV MFMAs;
// full unroll. All other kernels byte-identical to R5.
// ---------------------------------------------------------------------------

#define ACT_N   2097152
#define OFF_ACT0 0
#define OFF_ACT1 (ACT_N)
#define OFF_QB   (2*ACT_N)   // u16[16384*16]
#define OFF_KB   (3*ACT_N)
#define OFF_VT   (4*ACT_N)
#define OFF_ABF  (5*ACT_N)   // u16[16384*128]
#define OFF_MF   (6*ACT_N)
#define OFF_WB   (6*ACT_N + 16384)            // u16[10*16384]
#define OFF_DW8  (6*ACT_N + 16384 + 81920)    // float[4096]

typedef __attribute__((ext_vector_type(8)))  short bf16x8;
typedef __attribute__((ext_vector_type(16))) float f32x16;
typedef __attribute__((ext_vector_type(4)))  float f32x4;

static __device__ __forceinline__ unsigned int f2bf(float f) {
    unsigned int u = __float_as_uint(f);
    return (u + 0x7fffu + ((u >> 16) & 1u)) >> 16;
}
static __device__ __forceinline__ unsigned int pk2(float a, float b) {
    return f2bf(a) | (f2bf(b) << 16);
}

// swizzled byte offset of 16B granule g in row `row` of a [*][128 bf16] tile
#define GOFF(row, g) (((row) << 8) + ((((g) ^ ((row) & 15))) << 4))

// 0.25 * log2(e) : folds the 1/sqrt(DK) scale AND the exp->exp2 conversion
#define QSCALE 0.3606737602222409f

// ---------------------------------------------------------------------------
// k_prep: 0..9 convert 10 weight mats fp32->bf16 [o][c]; 10 additive mask; 11 dw8
// ---------------------------------------------------------------------------
__global__ __launch_bounds__(256) void k_prep(
    const float* __restrict__ pw, const float* __restrict__ wq,
    const float* __restrict__ wk, const float* __restrict__ wv_,
    const float* __restrict__ wo, const float* __restrict__ w1,
    const float* __restrict__ w2, const unsigned char* __restrict__ mask,
    const float* __restrict__ dwsrc,
    unsigned short* __restrict__ wb, float* __restrict__ maskf,
    float* __restrict__ dw8)
{
    int blk = blockIdx.x, t = threadIdx.x;
    if (blk < 10) {
        const float* src;
        if (blk < 4)       src = pw + blk * 16384;
        else if (blk == 4) src = wq;
        else if (blk == 5) src = wk;
        else if (blk == 6) src = wv_;
        else if (blk == 7) src = wo;
        else if (blk == 8) src = w1;
        else               src = w2;
        unsigned short* dst = wb + blk * 16384;
        for (int i = t * 8; i < 16384; i += 2048) {
            float4 a = *(const float4*)(src + i);
            float4 c = *(const float4*)(src + i + 4);
            uint4 v;
            v.x = pk2(a.x, a.y); v.y = pk2(a.z, a.w);
            v.z = pk2(c.x, c.y); v.w = pk2(c.z, c.w);
            *(uint4*)(dst + i) = v;
        }
    } else if (blk == 10) {
        for (int i = t; i < 16384; i += 256)
            maskf[i] = mask[i] ? -3.0e38f : 0.0f;   // additive, exp2 domain
    } else {
        for (int i = t; i < 4096; i += 256) {
            int n = i >> 3, tap = i & 7;
            dw8[i] = (tap < 7) ? dwsrc[n * 7 + tap] : 0.0f;
        }
    }
}

// ---------------------------------------------------------------------------
// k_pe: float4-vectorized
// ---------------------------------------------------------------------------
__global__ __launch_bounds__(256) void k_pe(const float* __restrict__ x,
                                            float* __restrict__ out)
{
    int i4 = blockIdx.x * 256 + threadIdx.x;   // < 524288
    int base = i4 * 4;
    int l = base & 1023;
    int c = (base >> 10) & 127;
    float e = (float)(c & ~1);
    float fb = exp2f(e * (-13.287712379549449f / 128.0f));
    float freq = (c & 1) ? -fb : fb;
    float ph   = (c & 1) ? 1.5707963267948966f : 0.0f;
    float4 xv = ((const float4*)x)[i4];
    float4 o;
    o.x = xv.x + sinf((float)l * freq + ph);
    o.y = xv.y + sinf((float)(l + 1) * freq + ph);
    o.z = xv.z + sinf((float)(l + 2) * freq + ph);
    o.w = xv.w + sinf((float)(l + 3) * freq + ph);
    ((float4*)out)[i4] = o;
}

// ---------------------------------------------------------------------------
// k_conv (unchanged)
// ---------------------------------------------------------------------------
__global__ __launch_bounds__(512) void k_conv(
    const float* __restrict__ in, float* __restrict__ out,
    const unsigned short* __restrict__ wb,   // bf16 [128 o][128 c]
    const float* __restrict__ dw8,           // [128][8]
    const float* __restrict__ pb,
    const float* __restrict__ g, const float* __restrict__ nbv)
{
    __shared__ unsigned short Wl[16384];
    __shared__ unsigned short Xl[8192];
    __shared__ float part[560];
    __shared__ float muL[70], rsL[70];

    const int b  = blockIdx.x >> 4;
    const int l0 = (blockIdx.x & 15) << 6;
    const int t  = threadIdx.x;
    const int lane = t & 63;
    const int w = __builtin_amdgcn_readfirstlane(t >> 6);
    const float* xb = in + b * 131072;

    {
        const uint4* src = (const uint4*)wb;
        #pragma unroll
        for (int i = 0; i < 4; ++i) {
            int gi = t + i * 512;
            uint4 v = src[gi];
            int row = gi >> 4, c16 = gi & 15;
            *(uint4*)((char*)Wl + GOFF(row, c16)) = v;
        }
    }
    if (t < 280) {
        int col = t >> 2, sl = t & 3;
        int gl = l0 - 3 + col;
        float s = 0.f, ss = 0.f;
        if ((unsigned)gl < 1024u) {
            for (int c = sl * 32; c < sl * 32 + 32; ++c) {
                float v = xb[c * 1024 + gl];
                s += v; ss = fmaf(v, v, ss);
            }
        }
        part[col * 8 + sl * 2]     = s;
        part[col * 8 + sl * 2 + 1] = ss;
    }
    __syncthreads();
    if (t < 70) {
        int gl = l0 - 3 + t;
        if ((unsigned)gl < 1024u) {
            float s  = part[t*8] + part[t*8+2] + part[t*8+4] + part[t*8+6];
            float ss = part[t*8+1] + part[t*8+3] + part[t*8+5] + part[t*8+7];
            float mu = s * 0.0078125f;
            float var = ss * 0.0078125f - mu * mu;
            muL[t] = mu; rsL[t] = rsqrtf(var + 1e-5f);
        } else { muL[t] = 0.f; rsL[t] = 0.f; }
    }
    __syncthreads();

    {
        const int l = lane;
        const int gl = l0 + l;
        float m[7], rf[7], vm[7];
        int pofs[7];
        #pragma unroll
        for (int j = 0; j < 7; ++j) {
            int p = gl - 3 + j;
            m[j]  = muL[l + j];
            rf[j] = rsL[l + j];
            vm[j] = ((unsigned)p < 1024u) ? 1.f : 0.f;
            pofs[j] = min(max(p, 0), 1023);
        }
        #pragma unroll
        for (int s = 0; s < 2; ++s) {
            int c0 = w * 16 + s * 8;
            unsigned int pk[4];
            #pragma unroll
            for (int cp = 0; cp < 4; ++cp) {
                float y2[2];
                #pragma unroll
                for (int ci = 0; ci < 2; ++ci) {
                    int c = c0 + cp * 2 + ci;
                    const float* xr = xb + c * 1024;
                    const float* dr = dw8 + c * 8;
                    float S1 = 0.f, S2 = 0.f;
                    #pragma unroll
                    for (int j = 0; j < 7; ++j) {
                        float xv = xr[pofs[j]];
                        float u = (xv - m[j]) * rf[j];
                        float dwv = dr[j];
                        S1 = fmaf(dwv, u,     S1);
                        S2 = fmaf(dwv, vm[j], S2);
                    }
                    y2[ci] = g[c] * S1 + nbv[c] * S2;
                }
                pk[cp] = pk2(y2[0], y2[1]);
            }
            *(uint4*)((char*)Xl + GOFF(l, (c0 >> 3))) = *(uint4*)pk;
        }
    }
    __syncthreads();

    const int l31 = lane & 31, hi = lane >> 5;
    const int ow = w >> 1, lh = w & 1;
    bf16x8 af[8];
    #pragma unroll
    for (int kc = 0; kc < 8; ++kc)
        af[kc] = *(const bf16x8*)((char*)Wl + GOFF(ow * 32 + l31, kc * 2 + hi));
    f32x16 acc;
    #pragma unroll
    for (int i = 0; i < 16; ++i) acc[i] = 0.f;
    #pragma unroll
    for (int kc = 0; kc < 8; ++kc) {
        bf16x8 bx = *(const bf16x8*)((char*)Xl + GOFF(lh * 32 + l31, kc * 2 + hi));
        acc = __builtin_amdgcn_mfma_f32_32x32x16_bf16(af[kc], bx, acc, 0, 0, 0);
    }
    float* ob = out + b * 131072;
    const int lg = l0 + lh * 32 + l31;
    #pragma unroll
    for (int r = 0; r < 16; ++r) {
        int o = ow * 32 + (r & 3) + 8 * (r >> 2) + 4 * hi;
        ob[o * 1024 + lg] = fmaxf(acc[r] + pb[o], 0.f) + xb[o * 1024 + lg];
    }
}

// ---------------------------------------------------------------------------
// k_qkv (unchanged)
// ---------------------------------------------------------------------------
__global__ __launch_bounds__(512) void k_qkv(
    const float* __restrict__ in, const unsigned short* __restrict__ wb,
    const float* __restrict__ bq, const float* __restrict__ bk,
    const float* __restrict__ bv,
    const float* __restrict__ g, const float* __restrict__ nbv,
    unsigned short* __restrict__ qb, unsigned short* __restrict__ kb,
    unsigned short* __restrict__ vt)
{
    __shared__ unsigned short Wl[16384];
    __shared__ unsigned short Xl[8192];
    __shared__ unsigned short vs[8][1280];
    __shared__ float part[1024];
    __shared__ float muL[64], rsL[64];

    const int b  = blockIdx.x >> 4;
    const int l0 = (blockIdx.x & 15) << 6;
    const int t  = threadIdx.x;
    const int lane = t & 63;
    const int w = __builtin_amdgcn_readfirstlane(t >> 6);
    const float* xb = in + b * 131072;

    {
        const uint4* src = (const uint4*)wb;
        #pragma unroll
        for (int i = 0; i < 4; ++i) {
            int gi = t + i * 512;
            uint4 v = src[gi];
            int row = gi >> 4, c16 = gi & 15;
            *(uint4*)((char*)Wl + GOFF(row, c16)) = v;
        }
    }
    {
        int col = t >> 3, sl = t & 7;
        float s = 0.f, ss = 0.f;
        for (int c = sl * 16; c < sl * 16 + 16; ++c) {
            float v = xb[c * 1024 + l0 + col];
            s += v; ss = fmaf(v, v, ss);
        }
        part[col * 16 + sl * 2]     = s;
        part[col * 16 + sl * 2 + 1] = ss;
    }
    __syncthreads();
    if (t < 64) {
        float s = 0.f, ss = 0.f;
        #pragma unroll
        for (int j = 0; j < 8; ++j) { s += part[t*16 + j*2]; ss += part[t*16 + j*2 + 1]; }
        float mu = s * 0.0078125f;
        float var = ss * 0.0078125f - mu * mu;
        muL[t] = mu; rsL[t] = rsqrtf(var + 1e-5f);
    }
    __syncthreads();
    {
        const int l = lane;
        float mu = muL[l], rs = rsL[l];
        #pragma unroll
        for (int s = 0; s < 2; ++s) {
            int c0 = w * 16 + s * 8;
            unsigned int pk[4];
            #pragma unroll
            for (int cp = 0; cp < 4; ++cp) {
                int c = c0 + cp * 2;
                float v0 = (xb[c * 1024 + l0 + l]       - mu) * rs * g[c]     + nbv[c];
                float v1 = (xb[(c + 1) * 1024 + l0 + l] - mu) * rs * g[c + 1] + nbv[c + 1];
                pk[cp] = pk2(v0, v1);
            }
            *(uint4*)((char*)Xl + GOFF(l, (c0 >> 3))) = *(uint4*)pk;
        }
    }
    __syncthreads();

    const int l31 = lane & 31, hi = lane >> 5;
    const int ow = w >> 1, lh = w & 1;
    const int lg = l0 + lh * 32 + l31;

    for (int p = 0; p < 3; ++p) {
        uint4 pw4[4];
        if (p < 2) {
            const uint4* src = (const uint4*)(wb + (p + 1) * 16384);
            #pragma unroll
            for (int i = 0; i < 4; ++i) pw4[i] = src[t + i * 512];
        }
        bf16x8 af[8];
        #pragma unroll
        for (int kc = 0; kc < 8; ++kc)
            af[kc] = *(const bf16x8*)((char*)Wl + GOFF(ow * 32 + l31, kc * 2 + hi));
        f32x16 acc;
        #pragma unroll
        for (int i = 0; i < 16; ++i) acc[i] = 0.f;
        #pragma unroll
        for (int kc = 0; kc < 8; ++kc) {
            bf16x8 bx = *(const bf16x8*)((char*)Xl + GOFF(lh * 32 + l31, kc * 2 + hi));
            acc = __builtin_amdgcn_mfma_f32_32x32x16_bf16(af[kc], bx, acc, 0, 0, 0);
        }

        if (p < 2) {
            const float* bias = (p == 0) ? bq : bk;
            unsigned short* dst = (p == 0) ? qb : kb;
            const float scl = (p == 0) ? QSCALE : 1.0f;
            unsigned int pk0[4], pk1[4];
            #pragma unroll
            for (int j2 = 0; j2 < 4; ++j2) {
                int r = j2 * 2;
                int o0 = ow * 32 + (r & 3) + 8 * (r >> 2) + 4 * hi;
                pk0[j2] = pk2((acc[r] + bias[o0]) * scl,
                              (acc[r + 1] + bias[o0 + 1]) * scl);
                int r8 = r + 8;
                int o1 = ow * 32 + (r8 & 3) + 8 * (r8 >> 2) + 4 * hi;
                pk1[j2] = pk2((acc[r8] + bias[o1]) * scl,
                              (acc[r8 + 1] + bias[o1 + 1]) * scl);
            }
            int bh0 = b * 8 + 2 * ow;
            *(uint4*)(dst + ((size_t)bh0 * 1024 + lg) * 16 + hi * 8) = *(uint4*)pk0;
            *(uint4*)(dst + ((size_t)(bh0 + 1) * 1024 + lg) * 16 + hi * 8) = *(uint4*)pk1;
        } else {
            unsigned short* vsw = vs[w];
            #pragma unroll
            for (int r = 0; r < 16; ++r) {
                int orow = (r & 3) + 8 * (r >> 2) + 4 * hi;
                int o = ow * 32 + orow;
                vsw[orow * 40 + l31] = (unsigned short)f2bf(acc[r] + bv[o]);
            }
            int d32 = l31;
            uint4 v0 = *(uint4*)(vsw + d32 * 40 + hi * 16);
            uint4 v1 = *(uint4*)(vsw + d32 * 40 + hi * 16 + 8);
            int head = 2 * ow + (d32 >> 4), dd = d32 & 15;
            unsigned short* vp = vt + ((size_t)(b * 8 + head) * 16 + dd) * 1024
                                    + l0 + lh * 32 + hi * 16;
            *(uint4*)vp = v0; *(uint4*)(vp + 8) = v1;
        }
        __syncthreads();
        if (p < 2) {
            #pragma unroll
            for (int i = 0; i < 4; ++i) {
                int gi = t + i * 512;
                int row = gi >> 4, c16 = gi & 15;
                *(uint4*)((char*)Wl + GOFF(row, c16)) = pw4[i];
            }
            __syncthreads();
        }
    }
}

// ---------------------------------------------------------------------------
// k_attn (R6): single-buffer LDS (30.25KB -> 5 blocks/CU), T14 reg-prefetch,
// builtin exp2, setprio around PV MFMAs, full unroll.
// ---------------------------------------------------------------------------
__global__ __launch_bounds__(256) void k_attn(
    const unsigned short* __restrict__ qb, const unsigned short* __restrict__ kb,
    const unsigned short* __restrict__ vt, const float* __restrict__ madd,
    unsigned short* __restrict__ abf)
{
    __shared__ unsigned short Kl[4096];      // [plane*2048 + key*8]  8KB
    __shared__ unsigned short Vl[4224];      // [d*264 + key]         8.25KB
    __shared__ float Ml[1024];               // additive mask         4KB
    __shared__ unsigned int Pl[4][640];      // per-wave P/O scratch  10KB

    const int bh = blockIdx.x >> 3;
    const int b  = bh >> 3;
    const int h  = bh & 7;
    const int qbase = (blockIdx.x & 7) << 7;
    const int t = threadIdx.x;
    const int lane = t & 63;
    const int w = t >> 6;
    const int l31 = lane & 31, hi = lane >> 5;
    const int l15 = lane & 15, h2 = lane >> 4;
    const int qw = qbase + w * 32;

    const uint4* ksrc = (const uint4*)(kb + (size_t)bh * 16384);
    const unsigned short* vsrc = vt + (size_t)bh * 16384;

    const int d0v = t >> 5,          ko0 = t & 31;
    const int d1v = (t + 256) >> 5,  ko1 = (t + 256) & 31;
    const int kp0 = t & 1,        kk0 = t >> 1;
    const int kp1 = t & 1,        kk1 = (t + 256) >> 1;

    ((float4*)Ml)[t] = ((const float4*)(madd + b * 1024))[t];

    bf16x8 qf;
    {
        uint4 qv = *(const uint4*)(qb + ((size_t)bh * 1024 + qw + l31) * 16 + hi * 8);
        union { uint4 u; bf16x8 v; } cvt; cvt.u = qv; qf = cvt.v;
    }
    bf16x8 ones;
    #pragma unroll
    for (int i = 0; i < 8; ++i) ones[i] = (short)0x3F80;

    // prologue: stage chunk 0
    {
        uint4 kr0 = ksrc[t], kr1 = ksrc[t + 256];
        uint4 vr0 = *(const uint4*)(vsrc + d0v * 1024 + ko0 * 8);
        uint4 vr1 = *(const uint4*)(vsrc + d1v * 1024 + ko1 * 8);
        *(uint4*)(&Kl[kp0 * 2048 + kk0 * 8]) = kr0;
        *(uint4*)(&Kl[kp1 * 2048 + kk1 * 8]) = kr1;
        *(uint4*)(&Vl[d0v * 264 + ko0 * 8]) = vr0;
        *(uint4*)(&Vl[d1v * 264 + ko1 * 8]) = vr1;
    }
    __syncthreads();

    f32x16 Z;
    #pragma unroll
    for (int i = 0; i < 16; ++i) Z[i] = 0.f;
    f32x4 O0, O1, Os0, Os1;
    #pragma unroll
    for (int i = 0; i < 4; ++i) { O0[i] = 0.f; O1[i] = 0.f; Os0[i] = 0.f; Os1[i] = 0.f; }

    unsigned int* myP = &Pl[w][0];

    for (int ch = 0; ch < 4; ++ch) {
        uint4 kr0, kr1, vr0, vr1;
        if (ch < 3) {   // T14: issue next-chunk loads now, write after barrier
            int cb = (ch + 1) * 512;
            int vb = (ch + 1) * 256;
            kr0 = ksrc[cb + t];
            kr1 = ksrc[cb + t + 256];
            vr0 = *(const uint4*)(vsrc + d0v * 1024 + vb + ko0 * 8);
            vr1 = *(const uint4*)(vsrc + d1v * 1024 + vb + ko1 * 8);
        }
        const int kgbase = ch * 256;

        #pragma unroll
        for (int kc = 0; kc < 8; ++kc) {
            bf16x8 kf = *(const bf16x8*)(Kl + hi * 2048 + (kc * 32 + l31) * 8);
            f32x16 S = __builtin_amdgcn_mfma_f32_32x32x16_bf16(kf, qf, Z, 0, 0, 0);

            #pragma unroll
            for (int rg = 0; rg < 4; ++rg) {
                float4 mm = *(const float4*)(Ml + kgbase + kc * 32 + rg * 8 + hi * 4);
                float p0 = __builtin_amdgcn_exp2f(S[rg * 4 + 0] + mm.x);
                float p1 = __builtin_amdgcn_exp2f(S[rg * 4 + 1] + mm.y);
                float p2 = __builtin_amdgcn_exp2f(S[rg * 4 + 2] + mm.z);
                float p3 = __builtin_amdgcn_exp2f(S[rg * 4 + 3] + mm.w);
                uint2 pwd;
                pwd.x = __builtin_amdgcn_perm(__float_as_uint(p1),
                                              __float_as_uint(p0), 0x07060302u);
                pwd.y = __builtin_amdgcn_perm(__float_as_uint(p3),
                                              __float_as_uint(p2), 0x07060302u);
                *(uint2*)((char*)myP + l31 * 80 + rg * 16 + hi * 8) = pwd;
            }

            bf16x8 vf  = *(const bf16x8*)(Vl + l15 * 264 + kc * 32 + h2 * 8);
            bf16x8 pa0 = *(const bf16x8*)((const char*)myP + l15 * 80 + h2 * 16);
            bf16x8 pa1 = *(const bf16x8*)((const char*)myP + (16 + l15) * 80 + h2 * 16);
            __builtin_amdgcn_s_setprio(1);
            O0  = __builtin_amdgcn_mfma_f32_16x16x32_bf16(pa0, vf,   O0,  0, 0, 0);
            O1  = __builtin_amdgcn_mfma_f32_16x16x32_bf16(pa1, vf,   O1,  0, 0, 0);
            Os0 = __builtin_amdgcn_mfma_f32_16x16x32_bf16(pa0, ones, Os0, 0, 0, 0);
            Os1 = __builtin_amdgcn_mfma_f32_16x16x32_bf16(pa1, ones, Os1, 0, 0, 0);
            __builtin_amdgcn_s_setprio(0);
        }

        if (ch < 3) {
            __syncthreads();   // all waves done reading Kl/Vl
            *(uint4*)(&Kl[kp0 * 2048 + kk0 * 8]) = kr0;
            *(uint4*)(&Kl[kp1 * 2048 + kk1 * 8]) = kr1;
            *(uint4*)(&Vl[d0v * 264 + ko0 * 8]) = vr0;
            *(uint4*)(&Vl[d1v * 264 + ko1 * 8]) = vr1;
            __syncthreads();   // writes visible
        }
    }

    // normalize: Os holds per-q row-sums (replicated across d-cols) -> lane-local
    unsigned short* myP16 = (unsigned short*)myP;
    #pragma unroll
    for (int r = 0; r < 4; ++r) {
        float i0 = __builtin_amdgcn_rcpf(Os0[r] + 1e-37f);
        float i1 = __builtin_amdgcn_rcpf(Os1[r] + 1e-37f);
        myP16[(h2 * 4 + r) * 20 + l15]        = (unsigned short)f2bf(O0[r] * i0);
        myP16[(16 + h2 * 4 + r) * 20 + l15]   = (unsigned short)f2bf(O1[r] * i1);
    }
    uint4 ov = *(const uint4*)(myP16 + l31 * 20 + hi * 8);
    *(uint4*)(abf + ((size_t)(b * 1024 + qw + l31)) * 128 + h * 16 + hi * 8) = ov;
}

// ---------------------------------------------------------------------------
// k_oproj (unchanged)
// ---------------------------------------------------------------------------
__global__ __launch_bounds__(512) void k_oproj(
    const unsigned short* __restrict__ abf, const unsigned short* __restrict__ wb,
    const float* __restrict__ bo, const float* __restrict__ res,
    float* __restrict__ out)
{
    __shared__ unsigned short Wl[16384];
    __shared__ unsigned short Xl[8192];
    const int b  = blockIdx.x >> 4;
    const int l0 = (blockIdx.x & 15) << 6;
    const int t  = threadIdx.x;
    const int lane = t & 63;
    const int w = __builtin_amdgcn_readfirstlane(t >> 6);

    {
        const uint4* src = (const uint4*)wb;
        #pragma unroll
        for (int i = 0; i < 4; ++i) {
            int gi = t + i * 512;
            uint4 v = src[gi];
            int row = gi >> 4, c16 = gi & 15;
            *(uint4*)((char*)Wl + GOFF(row, c16)) = v;
        }
        #pragma unroll
        for (int i = 0; i < 2; ++i) {
            int gi = t + i * 512;
            int row = gi >> 4, c16 = gi & 15;
            uint4 v = *(const uint4*)(abf + ((size_t)(b * 1024 + l0 + row)) * 128 + c16 * 8);
            *(uint4*)((char*)Xl + GOFF(row, c16)) = v;
        }
    }
    __syncthreads();

    const int l31 = lane & 31, hi = lane >> 5;
    const int ow = w >> 1, lh = w & 1;
    bf16x8 af[8];
    #pragma unroll
    for (int kc = 0; kc < 8; ++kc)
        af[kc] = *(const bf16x8*)((char*)Wl + GOFF(ow * 32 + l31, kc * 2 + hi));
    f32x16 acc;
    #pragma unroll
    for (int i = 0; i < 16; ++i) acc[i] = 0.f;
    #pragma unroll
    for (int kc = 0; kc < 8; ++kc) {
        bf16x8 bx = *(const bf16x8*)((char*)Xl + GOFF(lh * 32 + l31, kc * 2 + hi));
        acc = __builtin_amdgcn_mfma_f32_32x32x16_bf16(af[kc], bx, acc, 0, 0, 0);
    }
    const float* rb = res + b * 131072;
    float* ob = out + b * 131072;
    const int lg = l0 + lh * 32 + l31;
    #pragma unroll
    for (int r = 0; r < 16; ++r) {
        int o = ow * 32 + (r & 3) + 8 * (r >> 2) + 4 * hi;
        ob[o * 1024 + lg] = acc[r] + bo[o] + rb[o * 1024 + lg];
    }
}

// ---------------------------------------------------------------------------
// k_ffn (unchanged)
// ---------------------------------------------------------------------------
__global__ __launch_bounds__(512) void k_ffn(
    const float* __restrict__ in,
    const unsigned short* __restrict__ w1b, const unsigned short* __restrict__ w2b,
    const float* __restrict__ b1, const float* __restrict__ b2,
    const float* __restrict__ g, const float* __restrict__ nbv,
    float* __restrict__ out)
{
    __shared__ unsigned short Wl[16384];
    __shared__ unsigned short Xl[8192];
    __shared__ unsigned short Xl2[8192];
    __shared__ float part[1024];
    __shared__ float muL[64], rsL[64];

    const int b  = blockIdx.x >> 4;
    const int l0 = (blockIdx.x & 15) << 6;
    const int t  = threadIdx.x;
    const int lane = t & 63;
    const int w = __builtin_amdgcn_readfirstlane(t >> 6);
    const float* xb = in + b * 131072;

    {
        const uint4* src = (const uint4*)w1b;
        #pragma unroll
        for (int i = 0; i < 4; ++i) {
            int gi = t + i * 512;
            uint4 v = src[gi];
            int row = gi >> 4, c16 = gi & 15;
            *(uint4*)((char*)Wl + GOFF(row, c16)) = v;
        }
    }
    {
        int col = t >> 3, sl = t & 7;
        float s = 0.f, ss = 0.f;
        for (int c = sl * 16; c < sl * 16 + 16; ++c) {
            float v = xb[c * 1024 + l0 + col];
            s += v; ss = fmaf(v, v, ss);
        }
        part[col * 16 + sl * 2]     = s;
        part[col * 16 + sl * 2 + 1] = ss;
    }
    __syncthreads();
    if (t < 64) {
        float s = 0.f, ss = 0.f;
        #pragma unroll
        for (int j = 0; j < 8; ++j) { s += part[t*16 + j*2]; ss += part[t*16 + j*2 + 1]; }
        float mu = s * 0.0078125f;
        float var = ss * 0.0078125f - mu * mu;
        muL[t] = mu; rsL[t] = rsqrtf(var + 1e-5f);
    }
    __syncthreads();
    {
        const int l = lane;
        float mu = muL[l], rs = rsL[l];
        #pragma unroll
        for (int s = 0; s < 2; ++s) {
            int c0 = w * 16 + s * 8;
            unsigned int pk[4];
            #pragma unroll
            for (int cp = 0; cp < 4; ++cp) {
                int c = c0 + cp * 2;
                float v0 = (xb[c * 1024 + l0 + l]       - mu) * rs * g[c]     + nbv[c];
                float v1 = (xb[(c + 1) * 1024 + l0 + l] - mu) * rs * g[c + 1] + nbv[c + 1];
                pk[cp] = pk2(v0, v1);
            }
            *(uint4*)((char*)Xl + GOFF(l, (c0 >> 3))) = *(uint4*)pk;
        }
    }
    __syncthreads();

    const int l31 = lane & 31, hi = lane >> 5;
    const int ow = w >> 1, lh = w & 1;
    const int lrow = lh * 32 + l31;

    uint4 pw4[4];
    {
        const uint4* src = (const uint4*)w2b;
        #pragma unroll
        for (int i = 0; i < 4; ++i) pw4[i] = src[t + i * 512];
    }
    {
        bf16x8 af[8];
        #pragma unroll
        for (int kc = 0; kc < 8; ++kc)
            af[kc] = *(const bf16x8*)((char*)Wl + GOFF(ow * 32 + l31, kc * 2 + hi));
        f32x16 acc;
        #pragma unroll
        for (int i = 0; i < 16; ++i) acc[i] = 0.f;
        #pragma unroll
        for (int kc = 0; kc < 8; ++kc) {
            bf16x8 bx = *(const bf16x8*)((char*)Xl + GOFF(lrow, kc * 2 + hi));
            acc = __builtin_amdgcn_mfma_f32_32x32x16_bf16(af[kc], bx, acc, 0, 0, 0);
        }
        #pragma unroll
        for (int r = 0; r < 16; ++r) {
            int o = ow * 32 + (r & 3) + 8 * (r >> 2) + 4 * hi;
            float hval = fmaxf(acc[r] + b1[o], 0.f);
            *(unsigned short*)((char*)Xl2 + (lrow << 8)
                + ((((o >> 3) ^ (lrow & 15))) << 4) + ((o & 7) * 2)) =
                (unsigned short)f2bf(hval);
        }
    }
    __syncthreads();
    {
        #pragma unroll
        for (int i = 0; i < 4; ++i) {
            int gi = t + i * 512;
            int row = gi >> 4, c16 = gi & 15;
            *(uint4*)((char*)Wl + GOFF(row, c16)) = pw4[i];
        }
    }
    __syncthreads();
    {
        bf16x8 af[8];
        #pragma unroll
        for (int kc = 0; kc < 8; ++kc)
            af[kc] = *(const bf16x8*)((char*)Wl + GOFF(ow * 32 + l31, kc * 2 + hi));
        f32x16 acc;
        #pragma unroll
        for (int i = 0; i < 16; ++i) acc[i] = 0.f;
        #pragma unroll
        for (int kc = 0; kc < 8; ++kc) {
            bf16x8 bx = *(const bf16x8*)((char*)Xl2 + GOFF(lrow, kc * 2 + hi));
            acc = __builtin_amdgcn_mfma_f32_32x32x16_bf16(af[kc], bx, acc, 0, 0, 0);
        }
        float* ob = out + b * 131072;
        const int lg = l0 + lrow;
        #pragma unroll
        for (int r = 0; r < 16; ++r) {
            int o = ow * 32 + (r & 3) + 8 * (r >> 2) + 4 * hi;
            ob[o * 1024 + lg] = acc[r] + b2[o] + xb[o * 1024 + lg];
        }
    }
}

// ---------------------------------------------------------------------------
extern "C" void kernel_launch(void* const* d_in, const int* in_sizes, int n_in,
                              void* d_out, int out_size, void* d_ws, size_t ws_size,
                              hipStream_t stream)
{
    const float* x    = (const float*)d_in[0];
    const unsigned char* mask = (const unsigned char*)d_in[1];
    const float* dw_w = (const float*)d_in[2];
    const float* pw_w = (const float*)d_in[3];
    const float* pw_b = (const float*)d_in[4];
    const float* ng   = (const float*)d_in[5];
    const float* nb   = (const float*)d_in[6];
    const float* wq   = (const float*)d_in[7];
    const float* bq   = (const float*)d_in[8];
    const float* wk   = (const float*)d_in[9];
    const float* bk   = (const float*)d_in[10];
    const float* wv   = (const float*)d_in[11];
    const float* bv   = (const float*)d_in[12];
    const float* wo   = (const float*)d_in[13];
    const float* bo   = (const float*)d_in[14];
    const float* w1   = (const float*)d_in[15];
    const float* b1   = (const float*)d_in[16];
    const float* w2   = (const float*)d_in[17];
    const float* b2   = (const float*)d_in[18];

    float* ws   = (float*)d_ws;
    float* act0 = ws + OFF_ACT0;
    float* act1 = ws + OFF_ACT1;
    unsigned short* qb  = (unsigned short*)(ws + OFF_QB);
    unsigned short* kbp = (unsigned short*)(ws + OFF_KB);
    unsigned short* vtp = (unsigned short*)(ws + OFF_VT);
    unsigned short* abf = (unsigned short*)(ws + OFF_ABF);
    float* mf   = ws + OFF_MF;
    unsigned short* wb = (unsigned short*)(ws + OFF_WB);
    float* dw8  = ws + OFF_DW8;

    k_prep<<<12, 256, 0, stream>>>(pw_w, wq, wk, wv, wo, w1, w2, mask, dw_w,
                                   wb, mf, dw8);
    k_pe<<<2048, 256, 0, stream>>>(x, act0);

    k_conv<<<256, 512, 0, stream>>>(act0, act1, wb + 0 * 16384, dw8 + 0,
                                    pw_b + 0,   ng + 0,   nb + 0);
    k_conv<<<256, 512, 0, stream>>>(act1, act0, wb + 1 * 16384, dw8 + 1024,
                                    pw_b + 128, ng + 128, nb + 128);
    k_conv<<<256, 512, 0, stream>>>(act0, act1, wb + 2 * 16384, dw8 + 2048,
                                    pw_b + 256, ng + 256, nb + 256);
    k_conv<<<256, 512, 0, stream>>>(act1, act0, wb + 3 * 16384, dw8 + 3072,
                                    pw_b + 384, ng + 384, nb + 384);

    k_qkv<<<256, 512, 0, stream>>>(act0, wb + 4 * 16384, bq, bk, bv,
                                   ng + 4 * 128, nb + 4 * 128, qb, kbp, vtp);
    k_attn<<<1024, 256, 0, stream>>>(qb, kbp, vtp, mf, abf);
    k_oproj<<<256, 512, 0, stream>>>(abf, wb + 7 * 16384, bo, act0, act1);
    k_ffn<<<256, 512, 0, stream>>>(act1, wb + 8 * 16384, wb + 9 * 16384,
                                   b1, b2, ng + 5 * 128, nb + 5 * 128,
                                   (float*)d_out);
}